// Round 1
// baseline (398.348 us; speedup 1.0000x reference)
//
#include <hip/hip_runtime.h>
#include <hip/hip_bf16.h>
#include <math.h>

#define NN 512
#define DIMX 384
#define HH 8
#define SKK 16
#define SVV 16
#define PKK 4
#define PVV 4
#define PAIRD 128

#define SCALAR_SCALE 0.144337567297406f   // (3*16)^-0.5
#define POINT_SCALE  0.136082763487954f   // (12*4.5)^-0.5
#define PAIR_SCALE   0.577350269189626f   // 3^-0.5

// ---------------- Kernel 1: projections + frame transform ----------------
__global__ __launch_bounds__(256) void k_proj(
    const float* __restrict__ x, const float* __restrict__ rot, const float* __restrict__ trans,
    const float* __restrict__ Wsq, const float* __restrict__ Wsk, const float* __restrict__ Wsv,
    const float* __restrict__ Wpq, const float* __restrict__ Wpk, const float* __restrict__ Wpv,
    float* __restrict__ qs, float* __restrict__ ks, float* __restrict__ vs,
    float* __restrict__ qp, float* __restrict__ kp, float* __restrict__ vp)
{
    const int i0 = blockIdx.x * 8;
    const int tid = threadIdx.x;
    __shared__ float xs[8 * DIMX];       // 12 KB
    __shared__ float pl[3 * 8 * 96];     // 9 KB local point coords

    for (int f = tid; f < 8 * DIMX; f += 256) xs[f] = x[(size_t)i0 * DIMX + f];
    __syncthreads();

    const float* Ws[3]  = {Wsq, Wsk, Wsv};
    float* outs[3]      = {qs, ks, vs};
    for (int mc = tid; mc < 3 * 128; mc += 256) {
        int m = mc >> 7, c = mc & 127;
        const float* W = Ws[m];
        float acc[8] = {0,0,0,0,0,0,0,0};
        for (int k = 0; k < DIMX; ++k) {
            float wv = W[(size_t)k * 128 + c];
            #pragma unroll
            for (int r = 0; r < 8; ++r) acc[r] += xs[r * DIMX + k] * wv;
        }
        float* o = outs[m];
        #pragma unroll
        for (int r = 0; r < 8; ++r) o[(size_t)(i0 + r) * 128 + c] = acc[r];
    }

    const float* Wp[3] = {Wpq, Wpk, Wpv};
    for (int mc = tid; mc < 3 * 96; mc += 256) {
        int m = mc / 96, c = mc % 96;
        const float* W = Wp[m];
        float acc[8] = {0,0,0,0,0,0,0,0};
        for (int k = 0; k < DIMX; ++k) {
            float wv = W[(size_t)k * 96 + c];
            #pragma unroll
            for (int r = 0; r < 8; ++r) acc[r] += xs[r * DIMX + k] * wv;
        }
        #pragma unroll
        for (int r = 0; r < 8; ++r) pl[(m * 8 + r) * 96 + c] = acc[r];
    }
    __syncthreads();

    float* outp[3] = {qp, kp, vp};
    for (int pt = tid; pt < 3 * 8 * 32; pt += 256) {
        int m   = pt >> 8;        // 256 points per matrix
        int rem = pt & 255;
        int r   = rem >> 5;
        int p   = rem & 31;       // h*PK + d
        const float* l = &pl[(m * 8 + r) * 96 + p * 3];
        const float* R = &rot[(size_t)(i0 + r) * 9];
        const float* T = &trans[(size_t)(i0 + r) * 3];
        float l0 = l[0], l1 = l[1], l2 = l[2];
        float* o = outp[m] + (size_t)(i0 + r) * 96 + p * 3;
        #pragma unroll
        for (int c2 = 0; c2 < 3; ++c2)
            o[c2] = l0 * R[0 * 3 + c2] + l1 * R[1 * 3 + c2] + l2 * R[2 * 3 + c2] + T[c2];
    }
}

// ---------------- Kernel 2: fused logits ----------------
__global__ __launch_bounds__(256) void k_logits(
    const float* __restrict__ pair, const float* __restrict__ qs, const float* __restrict__ ks,
    const float* __restrict__ qp, const float* __restrict__ kp,
    const float* __restrict__ Wpair, const float* __restrict__ bpair, const float* __restrict__ pwts,
    float* __restrict__ logits)
{
    const int jt = blockIdx.x;     // 0..15
    const int i  = blockIdx.y;     // 0..511
    const int tid = threadIdx.x;
    const int j0 = jt * 32;

    __shared__ float ptile[32 * 129];   // +1 pad -> conflict-free column reads
    __shared__ float qs_s[128];
    __shared__ float qp_s[96];
    __shared__ float wp_s[PAIRD * HH];  // 4 KB

    const float* psrc = pair + ((size_t)i * NN + j0) * PAIRD;
    for (int f = tid; f < 32 * 128; f += 256) {
        int r = f >> 7, p = f & 127;
        ptile[r * 129 + p] = psrc[f];
    }
    for (int f = tid; f < PAIRD * HH; f += 256) wp_s[f] = Wpair[f];
    if (tid < 128) qs_s[tid] = qs[(size_t)i * 128 + tid];
    if (tid < 96)  qp_s[tid] = qp[(size_t)i * 96 + tid];
    __syncthreads();

    const int h  = tid >> 5;
    const int jj = tid & 31;
    const int j  = j0 + jj;

    float bias = 0.f;
    for (int p = 0; p < PAIRD; ++p)
        bias += ptile[jj * 129 + p] * wp_s[p * HH + h];

    float sc = 0.f;
    const float* kr = ks + (size_t)j * 128 + h * 16;
    const float* qr = &qs_s[h * 16];
    #pragma unroll
    for (int d = 0; d < 16; ++d) sc += qr[d] * kr[d];

    float d2 = 0.f;
    const float* kpr = kp + (size_t)j * 96 + h * 12;
    const float* qpr = &qp_s[h * 12];
    #pragma unroll
    for (int e = 0; e < 12; ++e) { float df = qpr[e] - kpr[e]; d2 += df * df; }

    float pw = log1pf(__expf(pwts[h]));
    float lg = sc * SCALAR_SCALE + (bias + bpair[h]) * PAIR_SCALE
             - 0.5f * POINT_SCALE * pw * d2;
    logits[((size_t)h * NN + i) * NN + j] = lg;
}

// ---------------- Kernel 3: row softmax ----------------
__global__ __launch_bounds__(256) void k_softmax(float* __restrict__ att)
{
    const int row = blockIdx.x;       // h*N + i
    const int tid = threadIdx.x;
    float* a = att + (size_t)row * NN;
    __shared__ float red[256];

    float v0 = a[tid], v1 = a[tid + 256];
    red[tid] = fmaxf(v0, v1);
    __syncthreads();
    for (int s = 128; s > 0; s >>= 1) {
        if (tid < s) red[tid] = fmaxf(red[tid], red[tid + s]);
        __syncthreads();
    }
    float m = red[0];
    __syncthreads();
    float e0 = __expf(v0 - m), e1 = __expf(v1 - m);
    red[tid] = e0 + e1;
    __syncthreads();
    for (int s = 128; s > 0; s >>= 1) {
        if (tid < s) red[tid] += red[tid + s];
        __syncthreads();
    }
    float inv = 1.f / red[0];
    a[tid] = e0 * inv;
    a[tid + 256] = e1 * inv;
}

// ---------------- Kernel 4: attention outputs -> feats ----------------
__global__ __launch_bounds__(256) void k_out(
    const float* __restrict__ att, const float* __restrict__ pair,
    const float* __restrict__ vs, const float* __restrict__ vp,
    const float* __restrict__ rot, const float* __restrict__ trans,
    float* __restrict__ feats)
{
    const int i = blockIdx.x;
    const int tid = threadIdx.x;
    __shared__ float at[8 * 516];      // padded stride (516%32==4) -> conflict-free
    __shared__ float red[8 * 128];
    __shared__ float pts[96];

    for (int f = tid; f < 8 * NN; f += 256) {
        int h = f >> 9, j = f & 511;
        at[h * 516 + j] = att[((size_t)h * NN + i) * NN + j];
    }
    __syncthreads();

    // Phase A: out_pair = sum_j attn[h,i,j] * pair[i,j,p]
    {
        const int p = tid & 127, g = tid >> 7;
        float acc[8] = {0,0,0,0,0,0,0,0};
        const float* prow = pair + (size_t)i * NN * PAIRD;
        for (int j = g; j < NN; j += 2) {
            float pr = prow[(size_t)j * PAIRD + p];
            #pragma unroll
            for (int h = 0; h < 8; ++h) acc[h] += at[h * 516 + j] * pr;
        }
        if (g == 0) {
            #pragma unroll
            for (int h = 0; h < 8; ++h) red[h * 128 + p] = acc[h];
        }
        __syncthreads();
        if (g == 1) {
            float* fo = feats + (size_t)i * 1280 + 256;
            #pragma unroll
            for (int h = 0; h < 8; ++h) fo[h * 128 + p] = red[h * 128 + p] + acc[h];
        }
        __syncthreads();
    }

    // Phase B: out_s and weighted points
    if (tid < 128) {
        int h = tid >> 4;
        float acc = 0.f;
        for (int j = 0; j < NN; ++j) acc += at[h * 516 + j] * vs[(size_t)j * 128 + tid];
        feats[(size_t)i * 1280 + tid] = acc;
    } else if (tid < 224) {
        int c = tid - 128;     // h*12 + e
        int h = c / 12;
        float acc = 0.f;
        for (int j = 0; j < NN; ++j) acc += at[h * 516 + j] * vp[(size_t)j * 96 + c];
        pts[c] = acc;
    }
    __syncthreads();

    // finalize: back to local frame + norms
    if (tid < 32) {
        const float* R = &rot[(size_t)i * 9];
        const float* T = &trans[(size_t)i * 3];
        float px = pts[tid * 3 + 0] - T[0];
        float py = pts[tid * 3 + 1] - T[1];
        float pz = pts[tid * 3 + 2] - T[2];
        float n2 = 0.f;
        float* fo = feats + (size_t)i * 1280;
        #pragma unroll
        for (int r = 0; r < 3; ++r) {
            float lr = px * R[r * 3 + 0] + py * R[r * 3 + 1] + pz * R[r * 3 + 2];
            fo[128 + tid * 3 + r] = lr;
            n2 += lr * lr;
        }
        fo[224 + tid] = sqrtf(n2 + 1e-8f);
    }
}

// ---------------- Kernel 5: final projection ----------------
__global__ __launch_bounds__(256) void k_final(
    const float* __restrict__ feats, const float* __restrict__ Wout,
    const float* __restrict__ bout, float* __restrict__ out)
{
    const int i0 = blockIdx.x * 8;
    const int tid = threadIdx.x;
    __shared__ float fl[8 * 1280];    // 40 KB
    for (int f = tid; f < 8 * 1280; f += 256) fl[f] = feats[(size_t)i0 * 1280 + f];
    __syncthreads();

    for (int c = tid; c < DIMX; c += 256) {
        float bv = bout[c];
        float acc[8];
        #pragma unroll
        for (int r = 0; r < 8; ++r) acc[r] = bv;
        for (int k = 0; k < 1280; ++k) {
            float wv = Wout[(size_t)k * DIMX + c];
            #pragma unroll
            for (int r = 0; r < 8; ++r) acc[r] += fl[r * 1280 + k] * wv;
        }
        #pragma unroll
        for (int r = 0; r < 8; ++r) out[(size_t)(i0 + r) * DIMX + c] = acc[r];
    }
}

extern "C" void kernel_launch(void* const* d_in, const int* in_sizes, int n_in,
                              void* d_out, int out_size, void* d_ws, size_t ws_size,
                              hipStream_t stream) {
    const float* x     = (const float*)d_in[0];
    const float* pair  = (const float*)d_in[1];
    const float* rot   = (const float*)d_in[2];
    const float* trans = (const float*)d_in[3];
    const float* Wsq   = (const float*)d_in[4];
    const float* Wsk   = (const float*)d_in[5];
    const float* Wsv   = (const float*)d_in[6];
    const float* Wpq   = (const float*)d_in[7];
    const float* Wpk   = (const float*)d_in[8];
    const float* Wpv   = (const float*)d_in[9];
    const float* Wpair = (const float*)d_in[10];
    const float* bpair = (const float*)d_in[11];
    const float* pwts  = (const float*)d_in[12];
    const float* Wout  = (const float*)d_in[13];
    const float* bout  = (const float*)d_in[14];

    float* ws    = (float*)d_ws;
    float* qs    = ws;                    // 512*128
    float* ks    = qs + 512 * 128;
    float* vs    = ks + 512 * 128;
    float* qp    = vs + 512 * 128;        // 512*96
    float* kp    = qp + 512 * 96;
    float* vp    = kp + 512 * 96;
    float* att   = vp + 512 * 96;         // 8*512*512
    float* feats = att + 8 * 512 * 512;   // 512*1280

    k_proj<<<64, 256, 0, stream>>>(x, rot, trans, Wsq, Wsk, Wsv, Wpq, Wpk, Wpv,
                                   qs, ks, vs, qp, kp, vp);
    k_logits<<<dim3(16, 512), 256, 0, stream>>>(pair, qs, ks, qp, kp,
                                                Wpair, bpair, pwts, att);
    k_softmax<<<8 * 512, 256, 0, stream>>>(att);
    k_out<<<512, 256, 0, stream>>>(att, pair, vs, vp, rot, trans, feats);
    k_final<<<64, 256, 0, stream>>>(feats, Wout, bout, (float*)d_out);
}

// Round 2
// 271.608 us; speedup vs baseline: 1.4666x; 1.4666x over previous
//
#include <hip/hip_runtime.h>
#include <hip/hip_bf16.h>
#include <math.h>

#define NN 512
#define DIMX 384
#define HH 8
#define SKK 16
#define SVV 16
#define PKK 4
#define PVV 4
#define PAIRD 128

#define SCALAR_SCALE 0.144337567297406f   // (3*16)^-0.5
#define POINT_SCALE  0.136082763487954f   // (12*4.5)^-0.5
#define PAIR_SCALE   0.577350269189626f   // 3^-0.5

#define KSL 8
#define KPER 160      // 1280 / KSL

// ---------------- Kernel 1: projections + frame transform ----------------
__global__ __launch_bounds__(256) void k_proj(
    const float* __restrict__ x, const float* __restrict__ rot, const float* __restrict__ trans,
    const float* __restrict__ Wsq, const float* __restrict__ Wsk, const float* __restrict__ Wsv,
    const float* __restrict__ Wpq, const float* __restrict__ Wpk, const float* __restrict__ Wpv,
    float* __restrict__ qs, float* __restrict__ ks, float* __restrict__ vs,
    float* __restrict__ qp, float* __restrict__ kp, float* __restrict__ vp)
{
    const int i0 = blockIdx.x * 8;
    const int tid = threadIdx.x;
    __shared__ float xs[8 * DIMX];       // 12 KB
    __shared__ float pl[3 * 8 * 96];     // 9 KB local point coords

    for (int f = tid; f < 8 * DIMX; f += 256) xs[f] = x[(size_t)i0 * DIMX + f];
    __syncthreads();

    const float* Ws[3]  = {Wsq, Wsk, Wsv};
    float* outs[3]      = {qs, ks, vs};
    for (int mc = tid; mc < 3 * 128; mc += 256) {
        int m = mc >> 7, c = mc & 127;
        const float* W = Ws[m];
        float acc[8] = {0,0,0,0,0,0,0,0};
        for (int k = 0; k < DIMX; ++k) {
            float wv = W[(size_t)k * 128 + c];
            #pragma unroll
            for (int r = 0; r < 8; ++r) acc[r] += xs[r * DIMX + k] * wv;
        }
        float* o = outs[m];
        #pragma unroll
        for (int r = 0; r < 8; ++r) o[(size_t)(i0 + r) * 128 + c] = acc[r];
    }

    const float* Wp[3] = {Wpq, Wpk, Wpv};
    for (int mc = tid; mc < 3 * 96; mc += 256) {
        int m = mc / 96, c = mc % 96;
        const float* W = Wp[m];
        float acc[8] = {0,0,0,0,0,0,0,0};
        for (int k = 0; k < DIMX; ++k) {
            float wv = W[(size_t)k * 96 + c];
            #pragma unroll
            for (int r = 0; r < 8; ++r) acc[r] += xs[r * DIMX + k] * wv;
        }
        #pragma unroll
        for (int r = 0; r < 8; ++r) pl[(m * 8 + r) * 96 + c] = acc[r];
    }
    __syncthreads();

    float* outp[3] = {qp, kp, vp};
    for (int pt = tid; pt < 3 * 8 * 32; pt += 256) {
        int m   = pt >> 8;
        int rem = pt & 255;
        int r   = rem >> 5;
        int p   = rem & 31;
        const float* l = &pl[(m * 8 + r) * 96 + p * 3];
        const float* R = &rot[(size_t)(i0 + r) * 9];
        const float* T = &trans[(size_t)(i0 + r) * 3];
        float l0 = l[0], l1 = l[1], l2 = l[2];
        float* o = outp[m] + (size_t)(i0 + r) * 96 + p * 3;
        #pragma unroll
        for (int c2 = 0; c2 < 3; ++c2)
            o[c2] = l0 * R[0 * 3 + c2] + l1 * R[1 * 3 + c2] + l2 * R[2 * 3 + c2] + T[c2];
    }
}

// ---------------- Kernel 2: fused logits ----------------
__global__ __launch_bounds__(256) void k_logits(
    const float* __restrict__ pair, const float* __restrict__ qs, const float* __restrict__ ks,
    const float* __restrict__ qp, const float* __restrict__ kp,
    const float* __restrict__ Wpair, const float* __restrict__ bpair, const float* __restrict__ pwts,
    float* __restrict__ logits)
{
    const int jt = blockIdx.x;     // 0..15
    const int i  = blockIdx.y;     // 0..511
    const int tid = threadIdx.x;
    const int j0 = jt * 32;

    __shared__ float ptile[32 * 129];
    __shared__ float qs_s[128];
    __shared__ float qp_s[96];
    __shared__ float wp_s[PAIRD * HH];

    const float* psrc = pair + ((size_t)i * NN + j0) * PAIRD;
    for (int f = tid; f < 32 * 128; f += 256) {
        int r = f >> 7, p = f & 127;
        ptile[r * 129 + p] = psrc[f];
    }
    for (int f = tid; f < PAIRD * HH; f += 256) wp_s[f] = Wpair[f];
    if (tid < 128) qs_s[tid] = qs[(size_t)i * 128 + tid];
    if (tid < 96)  qp_s[tid] = qp[(size_t)i * 96 + tid];
    __syncthreads();

    const int h  = tid >> 5;
    const int jj = tid & 31;
    const int j  = j0 + jj;

    float bias = 0.f;
    for (int p = 0; p < PAIRD; ++p)
        bias += ptile[jj * 129 + p] * wp_s[p * HH + h];

    float sc = 0.f;
    const float* kr = ks + (size_t)j * 128 + h * 16;
    const float* qr = &qs_s[h * 16];
    #pragma unroll
    for (int d = 0; d < 16; ++d) sc += qr[d] * kr[d];

    float d2 = 0.f;
    const float* kpr = kp + (size_t)j * 96 + h * 12;
    const float* qpr = &qp_s[h * 12];
    #pragma unroll
    for (int e = 0; e < 12; ++e) { float df = qpr[e] - kpr[e]; d2 += df * df; }

    float pw = log1pf(__expf(pwts[h]));
    float lg = sc * SCALAR_SCALE + (bias + bpair[h]) * PAIR_SCALE
             - 0.5f * POINT_SCALE * pw * d2;
    logits[((size_t)h * NN + i) * NN + j] = lg;
}

// ---------------- Kernel 3: row softmax ----------------
__global__ __launch_bounds__(256) void k_softmax(float* __restrict__ att)
{
    const int row = blockIdx.x;
    const int tid = threadIdx.x;
    float* a = att + (size_t)row * NN;
    __shared__ float red[256];

    float v0 = a[tid], v1 = a[tid + 256];
    red[tid] = fmaxf(v0, v1);
    __syncthreads();
    for (int s = 128; s > 0; s >>= 1) {
        if (tid < s) red[tid] = fmaxf(red[tid], red[tid + s]);
        __syncthreads();
    }
    float m = red[0];
    __syncthreads();
    float e0 = __expf(v0 - m), e1 = __expf(v1 - m);
    red[tid] = e0 + e1;
    __syncthreads();
    for (int s = 128; s > 0; s >>= 1) {
        if (tid < s) red[tid] += red[tid + s];
        __syncthreads();
    }
    float inv = 1.f / red[0];
    a[tid] = e0 * inv;
    a[tid + 256] = e1 * inv;
}

// ---------------- Kernel 4: attention outputs -> feats ----------------
__global__ __launch_bounds__(256) void k_out(
    const float* __restrict__ att, const float* __restrict__ pair,
    const float* __restrict__ vs, const float* __restrict__ vp,
    const float* __restrict__ rot, const float* __restrict__ trans,
    float* __restrict__ feats)
{
    const int i = blockIdx.x;
    const int tid = threadIdx.x;
    __shared__ float at[8 * 516];
    __shared__ float red[8 * 128];
    __shared__ float ptsp[2 * 96];

    for (int f = tid; f < 8 * NN; f += 256) {
        int h = f >> 9, j = f & 511;
        at[h * 516 + j] = att[((size_t)h * NN + i) * NN + j];
    }
    __syncthreads();

    // Phase A: out_pair = sum_j attn[h,i,j] * pair[i,j,p]
    {
        const int p = tid & 127, g = tid >> 7;
        float acc[8] = {0,0,0,0,0,0,0,0};
        const float* prow = pair + (size_t)i * NN * PAIRD;
        for (int j = g; j < NN; j += 2) {
            float pr = prow[(size_t)j * PAIRD + p];
            #pragma unroll
            for (int h = 0; h < 8; ++h) acc[h] += at[h * 516 + j] * pr;
        }
        if (g == 0) {
            #pragma unroll
            for (int h = 0; h < 8; ++h) red[h * 128 + p] = acc[h];
        }
        __syncthreads();
        if (g == 1) {
            float* fo = feats + (size_t)i * 1280 + 256;
            #pragma unroll
            for (int h = 0; h < 8; ++h) fo[h * 128 + p] = red[h * 128 + p] + acc[h];
        }
        __syncthreads();
    }

    // Phase B1: out_s, 2-way j split
    {
        const int c = tid & 127, g = tid >> 7;
        const int h = c >> 4;
        float acc = 0.f;
        const int jb = g * 256;
        for (int j = jb; j < jb + 256; ++j)
            acc += at[h * 516 + j] * vs[(size_t)j * 128 + c];
        red[g * 128 + c] = acc;
    }
    __syncthreads();
    if (tid < 128)
        feats[(size_t)i * 1280 + tid] = red[tid] + red[128 + tid];

    // Phase B2: weighted points, 2-way j split
    if (tid < 192) {
        const int c = tid % 96, g = tid / 96;
        const int h = c / 12;
        float acc = 0.f;
        const int jb = g * 256;
        for (int j = jb; j < jb + 256; ++j)
            acc += at[h * 516 + j] * vp[(size_t)j * 96 + c];
        ptsp[g * 96 + c] = acc;
    }
    __syncthreads();

    // finalize: back to local frame + norms
    if (tid < 32) {
        const float* R = &rot[(size_t)i * 9];
        const float* T = &trans[(size_t)i * 3];
        float px = ptsp[tid * 3 + 0] + ptsp[96 + tid * 3 + 0] - T[0];
        float py = ptsp[tid * 3 + 1] + ptsp[96 + tid * 3 + 1] - T[1];
        float pz = ptsp[tid * 3 + 2] + ptsp[96 + tid * 3 + 2] - T[2];
        float n2 = 0.f;
        float* fo = feats + (size_t)i * 1280;
        #pragma unroll
        for (int r = 0; r < 3; ++r) {
            float lr = px * R[r * 3 + 0] + py * R[r * 3 + 1] + pz * R[r * 3 + 2];
            fo[128 + tid * 3 + r] = lr;
            n2 += lr * lr;
        }
        fo[224 + tid] = sqrtf(n2 + 1e-8f);
    }
}

// ---------------- Kernel 5a: final GEMM, split-K, 128x128 tile ----------------
__global__ __launch_bounds__(256) void k_final_gemm(
    const float* __restrict__ feats, const float* __restrict__ Wout,
    float* __restrict__ partial)
{
    const int m0 = blockIdx.x * 128;      // 4 row tiles
    const int n0 = blockIdx.y * 128;      // 3 col tiles
    const int ks = blockIdx.z;            // KSL slices
    const int tid = threadIdx.x;
    const int k0 = ks * KPER;
    __shared__ float As[16][132];         // [k][m], transposed store, pad->2-way max
    __shared__ float Bs[16][132];         // [k][n], aligned float4 rows
    const int tx = tid & 15, ty = tid >> 4;
    float acc[8][8] = {};

    for (int kt = 0; kt < KPER; kt += 16) {
        #pragma unroll
        for (int it = 0; it < 2; ++it) {
            const int l = tid + it * 256;
            const int row = l >> 2, kq = l & 3;
            float4 a = *(const float4*)&feats[(size_t)(m0 + row) * 1280 + k0 + kt + kq * 4];
            As[kq * 4 + 0][row] = a.x; As[kq * 4 + 1][row] = a.y;
            As[kq * 4 + 2][row] = a.z; As[kq * 4 + 3][row] = a.w;
            const int kk = l >> 5, nq = l & 31;
            float4 b = *(const float4*)&Wout[(size_t)(k0 + kt + kk) * 384 + n0 + nq * 4];
            *(float4*)&Bs[kk][nq * 4] = b;
        }
        __syncthreads();
        #pragma unroll
        for (int k = 0; k < 16; ++k) {
            float4 a0 = *(const float4*)&As[k][ty * 8];
            float4 a1 = *(const float4*)&As[k][ty * 8 + 4];
            float4 b0 = *(const float4*)&Bs[k][tx * 8];
            float4 b1 = *(const float4*)&Bs[k][tx * 8 + 4];
            float am[8] = {a0.x, a0.y, a0.z, a0.w, a1.x, a1.y, a1.z, a1.w};
            float bn[8] = {b0.x, b0.y, b0.z, b0.w, b1.x, b1.y, b1.z, b1.w};
            #pragma unroll
            for (int r = 0; r < 8; ++r)
                #pragma unroll
                for (int c = 0; c < 8; ++c)
                    acc[r][c] += am[r] * bn[c];
        }
        __syncthreads();
    }
    float* po = partial + (size_t)ks * (512 * 384);
    #pragma unroll
    for (int r = 0; r < 8; ++r) {
        *(float4*)&po[(size_t)(m0 + ty * 8 + r) * 384 + n0 + tx * 8]     = *(float4*)&acc[r][0];
        *(float4*)&po[(size_t)(m0 + ty * 8 + r) * 384 + n0 + tx * 8 + 4] = *(float4*)&acc[r][4];
    }
}

// ---------------- Kernel 5b: split-K reduce + bias ----------------
__global__ __launch_bounds__(256) void k_reduce(
    const float* __restrict__ partial, const float* __restrict__ bout,
    float* __restrict__ out)
{
    const int f = blockIdx.x * 256 + threadIdx.x;   // float4 index; 49152 total
    const int e = f * 4;
    const int col = e % 384;
    float4 acc = *(const float4*)&bout[col];
    #pragma unroll
    for (int s = 0; s < KSL; ++s) {
        float4 p = *(const float4*)&partial[(size_t)s * (512 * 384) + e];
        acc.x += p.x; acc.y += p.y; acc.z += p.z; acc.w += p.w;
    }
    *(float4*)&out[e] = acc;
}

extern "C" void kernel_launch(void* const* d_in, const int* in_sizes, int n_in,
                              void* d_out, int out_size, void* d_ws, size_t ws_size,
                              hipStream_t stream) {
    const float* x     = (const float*)d_in[0];
    const float* pair  = (const float*)d_in[1];
    const float* rot   = (const float*)d_in[2];
    const float* trans = (const float*)d_in[3];
    const float* Wsq   = (const float*)d_in[4];
    const float* Wsk   = (const float*)d_in[5];
    const float* Wsv   = (const float*)d_in[6];
    const float* Wpq   = (const float*)d_in[7];
    const float* Wpk   = (const float*)d_in[8];
    const float* Wpv   = (const float*)d_in[9];
    const float* Wpair = (const float*)d_in[10];
    const float* bpair = (const float*)d_in[11];
    const float* pwts  = (const float*)d_in[12];
    const float* Wout  = (const float*)d_in[13];
    const float* bout  = (const float*)d_in[14];

    float* ws      = (float*)d_ws;
    float* qs      = ws;                    // 512*128
    float* ks      = qs + 512 * 128;
    float* vs      = ks + 512 * 128;
    float* qp      = vs + 512 * 128;        // 512*96
    float* kp      = qp + 512 * 96;
    float* vp      = kp + 512 * 96;
    float* att     = vp + 512 * 96;         // 8*512*512
    float* feats   = att + 8 * 512 * 512;   // 512*1280
    float* partial = feats + 512 * 1280;    // KSL*512*384

    k_proj<<<64, 256, 0, stream>>>(x, rot, trans, Wsq, Wsk, Wsv, Wpq, Wpk, Wpv,
                                   qs, ks, vs, qp, kp, vp);
    k_logits<<<dim3(16, 512), 256, 0, stream>>>(pair, qs, ks, qp, kp,
                                                Wpair, bpair, pwts, att);
    k_softmax<<<8 * 512, 256, 0, stream>>>(att);
    k_out<<<512, 256, 0, stream>>>(att, pair, vs, vp, rot, trans, feats);
    k_final_gemm<<<dim3(4, 3, KSL), 256, 0, stream>>>(feats, Wout, partial);
    k_reduce<<<192, 256, 0, stream>>>(partial, bout, (float*)d_out);
}

// Round 3
// 201.362 us; speedup vs baseline: 1.9783x; 1.3489x over previous
//
#include <hip/hip_runtime.h>
#include <hip/hip_bf16.h>
#include <math.h>

#define NN 512
#define DIMX 384
#define HH 8
#define PAIRD 128

#define SCALAR_SCALE 0.144337567297406f   // (3*16)^-0.5
#define POINT_SCALE  0.136082763487954f   // (12*4.5)^-0.5
#define PAIR_SCALE   0.577350269189626f   // 3^-0.5

#define KSL 8
#define KPER 160      // 1280 / KSL

// ---------------- Kernel 1a: unified projection GEMM ----------------
// C[512 x 672] = x[512 x 384] @ [Wsq|Wsk|Wsv|Wpq|Wpk|Wpv]
// grid.x = 8 M-tiles of 64, grid.y = 21 N-tiles of 32
__global__ __launch_bounds__(256) void k_proj_gemm(
    const float* __restrict__ x,
    const float* __restrict__ Wsq, const float* __restrict__ Wsk, const float* __restrict__ Wsv,
    const float* __restrict__ Wpq, const float* __restrict__ Wpk, const float* __restrict__ Wpv,
    float* __restrict__ qs, float* __restrict__ ks, float* __restrict__ vs,
    float* __restrict__ plq, float* __restrict__ plk, float* __restrict__ plv)
{
    const int m0 = blockIdx.x * 64;
    const int t  = blockIdx.y;   // 0..20
    int ldw, c0;
    const float* W;
    float* out;
    if (t < 12) {
        const float* Ws[3] = {Wsq, Wsk, Wsv};
        float* outs[3] = {qs, ks, vs};
        W = Ws[t >> 2]; out = outs[t >> 2]; c0 = (t & 3) * 32; ldw = 128;
    } else {
        const int u = t - 12;
        const float* Wp[3] = {Wpq, Wpk, Wpv};
        float* outp[3] = {plq, plk, plv};
        W = Wp[u / 3]; out = outp[u / 3]; c0 = (u % 3) * 32; ldw = 96;
    }
    const int tid = threadIdx.x;
    __shared__ float xs[32][68];   // [k][m] transposed, 16B-aligned rows
    __shared__ float Bs[32][36];   // [k][n]
    const int tx = tid & 15, ty = tid >> 4;
    float acc[4][2] = {};

    for (int kt = 0; kt < DIMX; kt += 32) {
        #pragma unroll
        for (int it = 0; it < 2; ++it) {
            int l = tid + it * 256;
            int row = l >> 3, kq = l & 7;
            float4 a = *(const float4*)&x[(size_t)(m0 + row) * DIMX + kt + kq * 4];
            xs[kq*4+0][row] = a.x; xs[kq*4+1][row] = a.y;
            xs[kq*4+2][row] = a.z; xs[kq*4+3][row] = a.w;
        }
        {
            int kk = tid >> 3, nq = tid & 7;
            float4 b = *(const float4*)&W[(size_t)(kt + kk) * ldw + c0 + nq * 4];
            *(float4*)&Bs[kk][nq * 4] = b;
        }
        __syncthreads();
        #pragma unroll
        for (int k = 0; k < 32; ++k) {
            float4 a  = *(const float4*)&xs[k][ty * 4];
            float2 bv = *(const float2*)&Bs[k][tx * 2];
            acc[0][0] += a.x * bv.x; acc[0][1] += a.x * bv.y;
            acc[1][0] += a.y * bv.x; acc[1][1] += a.y * bv.y;
            acc[2][0] += a.z * bv.x; acc[2][1] += a.z * bv.y;
            acc[3][0] += a.w * bv.x; acc[3][1] += a.w * bv.y;
        }
        __syncthreads();
    }
    #pragma unroll
    for (int r = 0; r < 4; ++r) {
        float2 v = make_float2(acc[r][0], acc[r][1]);
        *(float2*)&out[(size_t)(m0 + ty * 4 + r) * ldw + c0 + tx * 2] = v;
    }
}

// ---------------- Kernel 1b: frame transform (local -> global points) ----------------
__global__ __launch_bounds__(256) void k_frames(
    const float* __restrict__ plq, const float* __restrict__ plk, const float* __restrict__ plv,
    const float* __restrict__ rot, const float* __restrict__ trans,
    float* __restrict__ qp, float* __restrict__ kp, float* __restrict__ vp)
{
    int g = blockIdx.x * 256 + threadIdx.x;   // 3*512*32
    int m = g >> 14;
    int rem = g & 16383;
    int i = rem >> 5;
    int p = rem & 31;
    const float* pl = (m == 0 ? plq : (m == 1 ? plk : plv));
    float*       o  = (m == 0 ? qp  : (m == 1 ? kp  : vp));
    const float* l = &pl[(size_t)i * 96 + p * 3];
    const float* R = &rot[(size_t)i * 9];
    const float* T = &trans[(size_t)i * 3];
    float l0 = l[0], l1 = l[1], l2 = l[2];
    float* op = o + (size_t)i * 96 + p * 3;
    #pragma unroll
    for (int c = 0; c < 3; ++c)
        op[c] = l0 * R[0 * 3 + c] + l1 * R[1 * 3 + c] + l2 * R[2 * 3 + c] + T[c];
}

// ---------------- Kernel 2: fused logits ----------------
__global__ __launch_bounds__(256) void k_logits(
    const float* __restrict__ pair, const float* __restrict__ qs, const float* __restrict__ ks,
    const float* __restrict__ qp, const float* __restrict__ kp,
    const float* __restrict__ Wpair, const float* __restrict__ bpair, const float* __restrict__ pwts,
    float* __restrict__ logits)
{
    const int jt = blockIdx.x;     // 0..15
    const int i  = blockIdx.y;     // 0..511
    const int tid = threadIdx.x;
    const int j0 = jt * 32;

    __shared__ float ptile[32 * 129];
    __shared__ float qs_s[128];
    __shared__ float qp_s[96];
    __shared__ float wp_s[PAIRD * HH];

    const float* psrc = pair + ((size_t)i * NN + j0) * PAIRD;
    for (int f = tid; f < 32 * 128; f += 256) {
        int r = f >> 7, p = f & 127;
        ptile[r * 129 + p] = psrc[f];
    }
    for (int f = tid; f < PAIRD * HH; f += 256) wp_s[f] = Wpair[f];
    if (tid < 128) qs_s[tid] = qs[(size_t)i * 128 + tid];
    if (tid < 96)  qp_s[tid] = qp[(size_t)i * 96 + tid];
    __syncthreads();

    const int h  = tid >> 5;
    const int jj = tid & 31;
    const int j  = j0 + jj;

    float bias = 0.f;
    for (int p = 0; p < PAIRD; ++p)
        bias += ptile[jj * 129 + p] * wp_s[p * HH + h];

    float sc = 0.f;
    const float* kr = ks + (size_t)j * 128 + h * 16;
    const float* qr = &qs_s[h * 16];
    #pragma unroll
    for (int d = 0; d < 16; ++d) sc += qr[d] * kr[d];

    float d2 = 0.f;
    const float* kpr = kp + (size_t)j * 96 + h * 12;
    const float* qpr = &qp_s[h * 12];
    #pragma unroll
    for (int e = 0; e < 12; ++e) { float df = qpr[e] - kpr[e]; d2 += df * df; }

    float pw = log1pf(__expf(pwts[h]));
    float lg = sc * SCALAR_SCALE + (bias + bpair[h]) * PAIR_SCALE
             - 0.5f * POINT_SCALE * pw * d2;
    logits[((size_t)h * NN + i) * NN + j] = lg;
}

// ---------------- Kernel 3: row softmax ----------------
__global__ __launch_bounds__(256) void k_softmax(float* __restrict__ att)
{
    const int row = blockIdx.x;
    const int tid = threadIdx.x;
    float* a = att + (size_t)row * NN;
    __shared__ float red[256];

    float v0 = a[tid], v1 = a[tid + 256];
    red[tid] = fmaxf(v0, v1);
    __syncthreads();
    for (int s = 128; s > 0; s >>= 1) {
        if (tid < s) red[tid] = fmaxf(red[tid], red[tid + s]);
        __syncthreads();
    }
    float m = red[0];
    __syncthreads();
    float e0 = __expf(v0 - m), e1 = __expf(v1 - m);
    red[tid] = e0 + e1;
    __syncthreads();
    for (int s = 128; s > 0; s >>= 1) {
        if (tid < s) red[tid] += red[tid + s];
        __syncthreads();
    }
    float inv = 1.f / red[0];
    a[tid] = e0 * inv;
    a[tid + 256] = e1 * inv;
}

// ---------------- Kernel 4: attention outputs -> feats ----------------
__global__ __launch_bounds__(256) void k_out(
    const float* __restrict__ att, const float* __restrict__ pair,
    const float* __restrict__ vs, const float* __restrict__ vp,
    const float* __restrict__ rot, const float* __restrict__ trans,
    float* __restrict__ feats)
{
    const int i = blockIdx.x;
    const int tid = threadIdx.x;
    __shared__ float at[8 * 516];
    __shared__ float red[8 * 128];
    __shared__ float ptsp[2 * 96];

    for (int f = tid; f < 8 * NN; f += 256) {
        int h = f >> 9, j = f & 511;
        at[h * 516 + j] = att[((size_t)h * NN + i) * NN + j];
    }
    __syncthreads();

    // Phase A: out_pair
    {
        const int p = tid & 127, g = tid >> 7;
        float acc[8] = {0,0,0,0,0,0,0,0};
        const float* prow = pair + (size_t)i * NN * PAIRD;
        for (int j = g; j < NN; j += 2) {
            float pr = prow[(size_t)j * PAIRD + p];
            #pragma unroll
            for (int h = 0; h < 8; ++h) acc[h] += at[h * 516 + j] * pr;
        }
        if (g == 0) {
            #pragma unroll
            for (int h = 0; h < 8; ++h) red[h * 128 + p] = acc[h];
        }
        __syncthreads();
        if (g == 1) {
            float* fo = feats + (size_t)i * 1280 + 256;
            #pragma unroll
            for (int h = 0; h < 8; ++h) fo[h * 128 + p] = red[h * 128 + p] + acc[h];
        }
        __syncthreads();
    }

    // Phase B1: out_s, 2-way j split
    {
        const int c = tid & 127, g = tid >> 7;
        const int h = c >> 4;
        float acc = 0.f;
        const int jb = g * 256;
        for (int j = jb; j < jb + 256; ++j)
            acc += at[h * 516 + j] * vs[(size_t)j * 128 + c];
        red[g * 128 + c] = acc;
    }
    __syncthreads();
    if (tid < 128)
        feats[(size_t)i * 1280 + tid] = red[tid] + red[128 + tid];

    // Phase B2: weighted points, 2-way j split
    if (tid < 192) {
        const int c = tid % 96, g = tid / 96;
        const int h = c / 12;
        float acc = 0.f;
        const int jb = g * 256;
        for (int j = jb; j < jb + 256; ++j)
            acc += at[h * 516 + j] * vp[(size_t)j * 96 + c];
        ptsp[g * 96 + c] = acc;
    }
    __syncthreads();

    if (tid < 32) {
        const float* R = &rot[(size_t)i * 9];
        const float* T = &trans[(size_t)i * 3];
        float px = ptsp[tid * 3 + 0] + ptsp[96 + tid * 3 + 0] - T[0];
        float py = ptsp[tid * 3 + 1] + ptsp[96 + tid * 3 + 1] - T[1];
        float pz = ptsp[tid * 3 + 2] + ptsp[96 + tid * 3 + 2] - T[2];
        float n2 = 0.f;
        float* fo = feats + (size_t)i * 1280;
        #pragma unroll
        for (int r = 0; r < 3; ++r) {
            float lr = px * R[r * 3 + 0] + py * R[r * 3 + 1] + pz * R[r * 3 + 2];
            fo[128 + tid * 3 + r] = lr;
            n2 += lr * lr;
        }
        fo[224 + tid] = sqrtf(n2 + 1e-8f);
    }
}

// ---------------- Kernel 5a: final GEMM, split-K, 128x128 tile ----------------
__global__ __launch_bounds__(256) void k_final_gemm(
    const float* __restrict__ feats, const float* __restrict__ Wout,
    float* __restrict__ partial)
{
    const int m0 = blockIdx.x * 128;
    const int n0 = blockIdx.y * 128;
    const int ks = blockIdx.z;
    const int tid = threadIdx.x;
    const int k0 = ks * KPER;
    __shared__ float As[16][132];
    __shared__ float Bs[16][132];
    const int tx = tid & 15, ty = tid >> 4;
    float acc[8][8] = {};

    for (int kt = 0; kt < KPER; kt += 16) {
        #pragma unroll
        for (int it = 0; it < 2; ++it) {
            const int l = tid + it * 256;
            const int row = l >> 2, kq = l & 3;
            float4 a = *(const float4*)&feats[(size_t)(m0 + row) * 1280 + k0 + kt + kq * 4];
            As[kq * 4 + 0][row] = a.x; As[kq * 4 + 1][row] = a.y;
            As[kq * 4 + 2][row] = a.z; As[kq * 4 + 3][row] = a.w;
            const int kk = l >> 5, nq = l & 31;
            float4 b = *(const float4*)&Wout[(size_t)(k0 + kt + kk) * 384 + n0 + nq * 4];
            *(float4*)&Bs[kk][nq * 4] = b;
        }
        __syncthreads();
        #pragma unroll
        for (int k = 0; k < 16; ++k) {
            float4 a0 = *(const float4*)&As[k][ty * 8];
            float4 a1 = *(const float4*)&As[k][ty * 8 + 4];
            float4 b0 = *(const float4*)&Bs[k][tx * 8];
            float4 b1 = *(const float4*)&Bs[k][tx * 8 + 4];
            float am[8] = {a0.x, a0.y, a0.z, a0.w, a1.x, a1.y, a1.z, a1.w};
            float bn[8] = {b0.x, b0.y, b0.z, b0.w, b1.x, b1.y, b1.z, b1.w};
            #pragma unroll
            for (int r = 0; r < 8; ++r)
                #pragma unroll
                for (int c = 0; c < 8; ++c)
                    acc[r][c] += am[r] * bn[c];
        }
        __syncthreads();
    }
    float* po = partial + (size_t)ks * (512 * 384);
    #pragma unroll
    for (int r = 0; r < 8; ++r) {
        *(float4*)&po[(size_t)(m0 + ty * 8 + r) * 384 + n0 + tx * 8]     = *(float4*)&acc[r][0];
        *(float4*)&po[(size_t)(m0 + ty * 8 + r) * 384 + n0 + tx * 8 + 4] = *(float4*)&acc[r][4];
    }
}

// ---------------- Kernel 5b: split-K reduce + bias ----------------
__global__ __launch_bounds__(256) void k_reduce(
    const float* __restrict__ partial, const float* __restrict__ bout,
    float* __restrict__ out)
{
    const int f = blockIdx.x * 256 + threadIdx.x;
    const int e = f * 4;
    const int col = e % 384;
    float4 acc = *(const float4*)&bout[col];
    #pragma unroll
    for (int s = 0; s < KSL; ++s) {
        float4 p = *(const float4*)&partial[(size_t)s * (512 * 384) + e];
        acc.x += p.x; acc.y += p.y; acc.z += p.z; acc.w += p.w;
    }
    *(float4*)&out[e] = acc;
}

extern "C" void kernel_launch(void* const* d_in, const int* in_sizes, int n_in,
                              void* d_out, int out_size, void* d_ws, size_t ws_size,
                              hipStream_t stream) {
    const float* x     = (const float*)d_in[0];
    const float* pair  = (const float*)d_in[1];
    const float* rot   = (const float*)d_in[2];
    const float* trans = (const float*)d_in[3];
    const float* Wsq   = (const float*)d_in[4];
    const float* Wsk   = (const float*)d_in[5];
    const float* Wsv   = (const float*)d_in[6];
    const float* Wpq   = (const float*)d_in[7];
    const float* Wpk   = (const float*)d_in[8];
    const float* Wpv   = (const float*)d_in[9];
    const float* Wpair = (const float*)d_in[10];
    const float* bpair = (const float*)d_in[11];
    const float* pwts  = (const float*)d_in[12];
    const float* Wout  = (const float*)d_in[13];
    const float* bout  = (const float*)d_in[14];

    float* ws      = (float*)d_ws;
    float* qs      = ws;                    // 512*128
    float* ks      = qs + 512 * 128;
    float* vs      = ks + 512 * 128;
    float* qp      = vs + 512 * 128;        // 512*96
    float* kp      = qp + 512 * 96;
    float* vp      = kp + 512 * 96;
    float* att     = vp + 512 * 96;         // 8*512*512
    float* feats   = att + 8 * 512 * 512;   // 512*1280
    float* partial = feats + 512 * 1280;    // KSL*512*384
    float* plq     = partial + KSL * 512 * 384;  // 512*96 each
    float* plk     = plq + 512 * 96;
    float* plv     = plk + 512 * 96;

    k_proj_gemm<<<dim3(8, 21), 256, 0, stream>>>(x, Wsq, Wsk, Wsv, Wpq, Wpk, Wpv,
                                                 qs, ks, vs, plq, plk, plv);
    k_frames<<<192, 256, 0, stream>>>(plq, plk, plv, rot, trans, qp, kp, vp);
    k_logits<<<dim3(16, 512), 256, 0, stream>>>(pair, qs, ks, qp, kp,
                                                Wpair, bpair, pwts, att);
    k_softmax<<<8 * 512, 256, 0, stream>>>(att);
    k_out<<<512, 256, 0, stream>>>(att, pair, vs, vp, rot, trans, feats);
    k_final_gemm<<<dim3(4, 3, KSL), 256, 0, stream>>>(feats, Wout, partial);
    k_reduce<<<192, 256, 0, stream>>>(partial, bout, (float*)d_out);
}

// Round 4
// 153.499 us; speedup vs baseline: 2.5951x; 1.3118x over previous
//
#include <hip/hip_runtime.h>
#include <hip/hip_bf16.h>
#include <math.h>

#define NN 512
#define DIMX 384
#define HH 8
#define PAIRD 128

#define SCALAR_SCALE 0.144337567297406f   // (3*16)^-0.5
#define POINT_SCALE  0.136082763487954f   // (12*4.5)^-0.5
#define PAIR_SCALE   0.577350269189626f   // 3^-0.5

#define KSL 8
#define KPER 160      // 1280 / KSL

// ---------------- Kernel 1a: unified projection GEMM ----------------
__global__ __launch_bounds__(256) void k_proj_gemm(
    const float* __restrict__ x,
    const float* __restrict__ Wsq, const float* __restrict__ Wsk, const float* __restrict__ Wsv,
    const float* __restrict__ Wpq, const float* __restrict__ Wpk, const float* __restrict__ Wpv,
    float* __restrict__ qs, float* __restrict__ ks, float* __restrict__ vs,
    float* __restrict__ plq, float* __restrict__ plk, float* __restrict__ plv)
{
    const int m0 = blockIdx.x * 64;
    const int t  = blockIdx.y;   // 0..20
    int ldw, c0;
    const float* W;
    float* out;
    if (t < 12) {
        const float* Ws[3] = {Wsq, Wsk, Wsv};
        float* outs[3] = {qs, ks, vs};
        W = Ws[t >> 2]; out = outs[t >> 2]; c0 = (t & 3) * 32; ldw = 128;
    } else {
        const int u = t - 12;
        const float* Wp[3] = {Wpq, Wpk, Wpv};
        float* outp[3] = {plq, plk, plv};
        W = Wp[u / 3]; out = outp[u / 3]; c0 = (u % 3) * 32; ldw = 96;
    }
    const int tid = threadIdx.x;
    __shared__ float xs[32][68];
    __shared__ float Bs[32][36];
    const int tx = tid & 15, ty = tid >> 4;
    float acc[4][2] = {};

    for (int kt = 0; kt < DIMX; kt += 32) {
        #pragma unroll
        for (int it = 0; it < 2; ++it) {
            int l = tid + it * 256;
            int row = l >> 3, kq = l & 7;
            float4 a = *(const float4*)&x[(size_t)(m0 + row) * DIMX + kt + kq * 4];
            xs[kq*4+0][row] = a.x; xs[kq*4+1][row] = a.y;
            xs[kq*4+2][row] = a.z; xs[kq*4+3][row] = a.w;
        }
        {
            int kk = tid >> 3, nq = tid & 7;
            float4 b = *(const float4*)&W[(size_t)(kt + kk) * ldw + c0 + nq * 4];
            *(float4*)&Bs[kk][nq * 4] = b;
        }
        __syncthreads();
        #pragma unroll
        for (int k = 0; k < 32; ++k) {
            float4 a  = *(const float4*)&xs[k][ty * 4];
            float2 bv = *(const float2*)&Bs[k][tx * 2];
            acc[0][0] += a.x * bv.x; acc[0][1] += a.x * bv.y;
            acc[1][0] += a.y * bv.x; acc[1][1] += a.y * bv.y;
            acc[2][0] += a.z * bv.x; acc[2][1] += a.z * bv.y;
            acc[3][0] += a.w * bv.x; acc[3][1] += a.w * bv.y;
        }
        __syncthreads();
    }
    #pragma unroll
    for (int r = 0; r < 4; ++r) {
        float2 v = make_float2(acc[r][0], acc[r][1]);
        *(float2*)&out[(size_t)(m0 + ty * 4 + r) * ldw + c0 + tx * 2] = v;
    }
}

// ---------------- Kernel 1b: frame transform ----------------
__global__ __launch_bounds__(256) void k_frames(
    const float* __restrict__ plq, const float* __restrict__ plk, const float* __restrict__ plv,
    const float* __restrict__ rot, const float* __restrict__ trans,
    float* __restrict__ qp, float* __restrict__ kp, float* __restrict__ vp)
{
    int g = blockIdx.x * 256 + threadIdx.x;
    int m = g >> 14;
    int rem = g & 16383;
    int i = rem >> 5;
    int p = rem & 31;
    const float* pl = (m == 0 ? plq : (m == 1 ? plk : plv));
    float*       o  = (m == 0 ? qp  : (m == 1 ? kp  : vp));
    const float* l = &pl[(size_t)i * 96 + p * 3];
    const float* R = &rot[(size_t)i * 9];
    const float* T = &trans[(size_t)i * 3];
    float l0 = l[0], l1 = l[1], l2 = l[2];
    float* op = o + (size_t)i * 96 + p * 3;
    #pragma unroll
    for (int c = 0; c < 3; ++c)
        op[c] = l0 * R[0 * 3 + c] + l1 * R[1 * 3 + c] + l2 * R[2 * 3 + c] + T[c];
}

// ---------------- Kernel 2: fused logits ----------------
__global__ __launch_bounds__(256) void k_logits(
    const float* __restrict__ pair, const float* __restrict__ qs, const float* __restrict__ ks,
    const float* __restrict__ qp, const float* __restrict__ kp,
    const float* __restrict__ Wpair, const float* __restrict__ bpair, const float* __restrict__ pwts,
    float* __restrict__ logits)
{
    const int jt = blockIdx.x;     // 0..15
    const int i  = blockIdx.y;     // 0..511
    const int tid = threadIdx.x;
    const int j0 = jt * 32;

    __shared__ float ptile[32 * 129];
    __shared__ float qs_s[128];
    __shared__ float qp_s[96];
    __shared__ float wp_s[PAIRD * HH];

    const float4* psrc4 = (const float4*)(pair + ((size_t)i * NN + j0) * PAIRD);
    #pragma unroll
    for (int it = 0; it < 4; ++it) {
        int l = tid + it * 256;          // 0..1023
        int r = l >> 5, p4 = l & 31;
        float4 v = psrc4[l];
        float* d = &ptile[r * 129 + p4 * 4];
        d[0] = v.x; d[1] = v.y; d[2] = v.z; d[3] = v.w;
    }
    ((float4*)wp_s)[tid] = ((const float4*)Wpair)[tid];
    if (tid < 32) ((float4*)qs_s)[tid] = ((const float4*)(qs + (size_t)i * 128))[tid];
    if (tid < 24) ((float4*)qp_s)[tid] = ((const float4*)(qp + (size_t)i * 96))[tid];
    __syncthreads();

    const int h  = tid >> 5;
    const int jj = tid & 31;
    const int j  = j0 + jj;

    float bias = 0.f;
    #pragma unroll 4
    for (int p = 0; p < PAIRD; ++p)
        bias += ptile[jj * 129 + p] * wp_s[p * HH + h];

    float sc = 0.f;
    const float4* kr4 = (const float4*)(ks + (size_t)j * 128 + h * 16);
    const float4* qr4 = (const float4*)&qs_s[h * 16];
    #pragma unroll
    for (int q = 0; q < 4; ++q) {
        float4 kq = kr4[q], qq = qr4[q];
        sc += qq.x * kq.x + qq.y * kq.y + qq.z * kq.z + qq.w * kq.w;
    }

    float d2 = 0.f;
    const float4* kp4 = (const float4*)(kp + (size_t)j * 96 + h * 12);
    const float4* qp4 = (const float4*)&qp_s[h * 12];
    #pragma unroll
    for (int q = 0; q < 3; ++q) {
        float4 kq = kp4[q], qq = qp4[q];
        float dx = qq.x - kq.x, dy = qq.y - kq.y, dz = qq.z - kq.z, dw = qq.w - kq.w;
        d2 += dx * dx + dy * dy + dz * dz + dw * dw;
    }

    float pw = log1pf(__expf(pwts[h]));
    float lg = sc * SCALAR_SCALE + (bias + bpair[h]) * PAIR_SCALE
             - 0.5f * POINT_SCALE * pw * d2;
    logits[((size_t)h * NN + i) * NN + j] = lg;
}

// ---------------- Kernel 4: softmax + attention outputs -> feats ----------------
// block = residue i. Stages logits, softmaxes in LDS, then float4 8-way-j
// accumulation for out_pair / out_s / points.
__global__ __launch_bounds__(256) void k_out(
    const float* __restrict__ logits, const float* __restrict__ pair,
    const float* __restrict__ vs, const float* __restrict__ vp,
    const float* __restrict__ rot, const float* __restrict__ trans,
    float* __restrict__ feats)
{
    const int i = blockIdx.x;
    const int tid = threadIdx.x;
    __shared__ float at[8 * 516];        // 16.5 KB, stride 516 (float4-aligned rows)
    __shared__ float red[8 * 8 * 128];   // 32 KB scratch, reused (disjoint regions for B1/B2)
    __shared__ float pts[96];
    float4* red4 = (float4*)red;

    // stage logits (float4)
    #pragma unroll
    for (int it = 0; it < 4; ++it) {
        int f = tid + it * 256;          // 0..1023
        int h = f >> 7, jq = f & 127;
        float4 v = *(const float4*)&logits[((size_t)h * NN + i) * NN + jq * 4];
        *(float4*)&at[h * 516 + jq * 4] = v;
    }
    __syncthreads();

    // in-LDS softmax: 32 lanes per head
    {
        const int h = tid >> 5, l = tid & 31;
        float4 vv[4];
        float m = -1e30f;
        #pragma unroll
        for (int q = 0; q < 4; ++q) {
            vv[q] = *(const float4*)&at[h * 516 + (l + q * 32) * 4];
            m = fmaxf(m, fmaxf(fmaxf(vv[q].x, vv[q].y), fmaxf(vv[q].z, vv[q].w)));
        }
        #pragma unroll
        for (int off = 16; off > 0; off >>= 1) m = fmaxf(m, __shfl_xor(m, off, 32));
        float s = 0.f;
        #pragma unroll
        for (int q = 0; q < 4; ++q) {
            vv[q].x = __expf(vv[q].x - m); vv[q].y = __expf(vv[q].y - m);
            vv[q].z = __expf(vv[q].z - m); vv[q].w = __expf(vv[q].w - m);
            s += vv[q].x + vv[q].y + vv[q].z + vv[q].w;
        }
        #pragma unroll
        for (int off = 16; off > 0; off >>= 1) s += __shfl_xor(s, off, 32);
        float inv = 1.f / s;
        #pragma unroll
        for (int q = 0; q < 4; ++q) {
            vv[q].x *= inv; vv[q].y *= inv; vv[q].z *= inv; vv[q].w *= inv;
            *(float4*)&at[h * 516 + (l + q * 32) * 4] = vv[q];
        }
    }
    __syncthreads();

    const int jj = tid >> 5;     // 0..7
    const int pq = tid & 31;     // float4 index

    // Phase A: out_pair
    {
        const float4* prow4 = (const float4*)(pair + (size_t)i * NN * PAIRD);
        float4 accA[8];
        #pragma unroll
        for (int h = 0; h < 8; ++h) accA[h] = make_float4(0, 0, 0, 0);
        for (int j = jj; j < NN; j += 8) {
            float4 pr = prow4[j * 32 + pq];
            #pragma unroll
            for (int h = 0; h < 8; ++h) {
                float a = at[h * 516 + j];
                accA[h].x += a * pr.x; accA[h].y += a * pr.y;
                accA[h].z += a * pr.z; accA[h].w += a * pr.w;
            }
        }
        #pragma unroll
        for (int h = 0; h < 8; ++h) red4[(jj * 8 + h) * 32 + pq] = accA[h];
    }
    __syncthreads();
    {   // reduce 8 jj-groups -> feats[out_pair]
        int h = tid >> 5, p4 = tid & 31;
        float4 s = red4[(0 * 8 + h) * 32 + p4];
        #pragma unroll
        for (int g = 1; g < 8; ++g) {
            float4 v = red4[(g * 8 + h) * 32 + p4];
            s.x += v.x; s.y += v.y; s.z += v.z; s.w += v.w;
        }
        ((float4*)&feats[(size_t)i * 1280 + 256])[tid] = s;
    }
    __syncthreads();

    // Phase B1: out_s (vs is L2-resident)
    {
        const float4* vs4 = (const float4*)vs;
        const int h = pq >> 2;
        float4 acc = make_float4(0, 0, 0, 0);
        for (int j = jj; j < NN; j += 8) {
            float4 v = vs4[j * 32 + pq];
            float a = at[h * 516 + j];
            acc.x += a * v.x; acc.y += a * v.y; acc.z += a * v.z; acc.w += a * v.w;
        }
        red4[jj * 32 + pq] = acc;
    }
    __syncthreads();
    // B1 reduce (threads 224..255) || Phase B2 accumulate (threads 0..191)
    if (tid >= 224) {
        int t = tid - 224;
        float4 s = red4[t];
        #pragma unroll
        for (int g = 1; g < 8; ++g) {
            float4 v = red4[g * 32 + t];
            s.x += v.x; s.y += v.y; s.z += v.z; s.w += v.w;
        }
        ((float4*)&feats[(size_t)i * 1280])[t] = s;
    } else if (tid < 192) {
        const float4* vp4 = (const float4*)vp;
        const int gj = tid / 24, pc = tid % 24;
        const int h = pc / 3;
        float4 acc = make_float4(0, 0, 0, 0);
        for (int j = gj; j < NN; j += 8) {
            float4 v = vp4[j * 24 + pc];
            float a = at[h * 516 + j];
            acc.x += a * v.x; acc.y += a * v.y; acc.z += a * v.z; acc.w += a * v.w;
        }
        red4[256 + gj * 24 + pc] = acc;    // disjoint from B1 region [0..255]
    }
    __syncthreads();
    if (tid < 24) {
        float4 s = red4[256 + tid];
        #pragma unroll
        for (int g = 1; g < 8; ++g) {
            float4 v = red4[256 + g * 24 + tid];
            s.x += v.x; s.y += v.y; s.z += v.z; s.w += v.w;
        }
        ((float4*)pts)[tid] = s;
    }
    __syncthreads();

    // finalize: back to local frame + norms
    if (tid < 32) {
        const float* R = &rot[(size_t)i * 9];
        const float* T = &trans[(size_t)i * 3];
        float px = pts[tid * 3 + 0] - T[0];
        float py = pts[tid * 3 + 1] - T[1];
        float pz = pts[tid * 3 + 2] - T[2];
        float n2 = 0.f;
        float* fo = feats + (size_t)i * 1280;
        #pragma unroll
        for (int r = 0; r < 3; ++r) {
            float lr = px * R[r * 3 + 0] + py * R[r * 3 + 1] + pz * R[r * 3 + 2];
            fo[128 + tid * 3 + r] = lr;
            n2 += lr * lr;
        }
        fo[224 + tid] = sqrtf(n2 + 1e-8f);
    }
}

// ---------------- Kernel 5a: final GEMM, split-K, 128x128 tile ----------------
__global__ __launch_bounds__(256) void k_final_gemm(
    const float* __restrict__ feats, const float* __restrict__ Wout,
    float* __restrict__ partial)
{
    const int m0 = blockIdx.x * 128;
    const int n0 = blockIdx.y * 128;
    const int ks = blockIdx.z;
    const int tid = threadIdx.x;
    const int k0 = ks * KPER;
    __shared__ float As[16][132];
    __shared__ float Bs[16][132];
    const int tx = tid & 15, ty = tid >> 4;
    float acc[8][8] = {};

    for (int kt = 0; kt < KPER; kt += 16) {
        #pragma unroll
        for (int it = 0; it < 2; ++it) {
            const int l = tid + it * 256;
            const int row = l >> 2, kq = l & 3;
            float4 a = *(const float4*)&feats[(size_t)(m0 + row) * 1280 + k0 + kt + kq * 4];
            As[kq * 4 + 0][row] = a.x; As[kq * 4 + 1][row] = a.y;
            As[kq * 4 + 2][row] = a.z; As[kq * 4 + 3][row] = a.w;
            const int kk = l >> 5, nq = l & 31;
            float4 b = *(const float4*)&Wout[(size_t)(k0 + kt + kk) * 384 + n0 + nq * 4];
            *(float4*)&Bs[kk][nq * 4] = b;
        }
        __syncthreads();
        #pragma unroll
        for (int k = 0; k < 16; ++k) {
            float4 a0 = *(const float4*)&As[k][ty * 8];
            float4 a1 = *(const float4*)&As[k][ty * 8 + 4];
            float4 b0 = *(const float4*)&Bs[k][tx * 8];
            float4 b1 = *(const float4*)&Bs[k][tx * 8 + 4];
            float am[8] = {a0.x, a0.y, a0.z, a0.w, a1.x, a1.y, a1.z, a1.w};
            float bn[8] = {b0.x, b0.y, b0.z, b0.w, b1.x, b1.y, b1.z, b1.w};
            #pragma unroll
            for (int r = 0; r < 8; ++r)
                #pragma unroll
                for (int c = 0; c < 8; ++c)
                    acc[r][c] += am[r] * bn[c];
        }
        __syncthreads();
    }
    float* po = partial + (size_t)ks * (512 * 384);
    #pragma unroll
    for (int r = 0; r < 8; ++r) {
        *(float4*)&po[(size_t)(m0 + ty * 8 + r) * 384 + n0 + tx * 8]     = *(float4*)&acc[r][0];
        *(float4*)&po[(size_t)(m0 + ty * 8 + r) * 384 + n0 + tx * 8 + 4] = *(float4*)&acc[r][4];
    }
}

// ---------------- Kernel 5b: split-K reduce + bias ----------------
__global__ __launch_bounds__(256) void k_reduce(
    const float* __restrict__ partial, const float* __restrict__ bout,
    float* __restrict__ out)
{
    const int f = blockIdx.x * 256 + threadIdx.x;
    const int e = f * 4;
    const int col = e % 384;
    float4 acc = *(const float4*)&bout[col];
    #pragma unroll
    for (int s = 0; s < KSL; ++s) {
        float4 p = *(const float4*)&partial[(size_t)s * (512 * 384) + e];
        acc.x += p.x; acc.y += p.y; acc.z += p.z; acc.w += p.w;
    }
    *(float4*)&out[e] = acc;
}

extern "C" void kernel_launch(void* const* d_in, const int* in_sizes, int n_in,
                              void* d_out, int out_size, void* d_ws, size_t ws_size,
                              hipStream_t stream) {
    const float* x     = (const float*)d_in[0];
    const float* pair  = (const float*)d_in[1];
    const float* rot   = (const float*)d_in[2];
    const float* trans = (const float*)d_in[3];
    const float* Wsq   = (const float*)d_in[4];
    const float* Wsk   = (const float*)d_in[5];
    const float* Wsv   = (const float*)d_in[6];
    const float* Wpq   = (const float*)d_in[7];
    const float* Wpk   = (const float*)d_in[8];
    const float* Wpv   = (const float*)d_in[9];
    const float* Wpair = (const float*)d_in[10];
    const float* bpair = (const float*)d_in[11];
    const float* pwts  = (const float*)d_in[12];
    const float* Wout  = (const float*)d_in[13];
    const float* bout  = (const float*)d_in[14];

    float* ws      = (float*)d_ws;
    float* qs      = ws;                    // 512*128
    float* ks      = qs + 512 * 128;
    float* vs      = ks + 512 * 128;
    float* qp      = vs + 512 * 128;        // 512*96
    float* kp      = qp + 512 * 96;
    float* vp      = kp + 512 * 96;
    float* att     = vp + 512 * 96;         // 8*512*512 (raw logits)
    float* feats   = att + 8 * 512 * 512;   // 512*1280
    float* partial = feats + 512 * 1280;    // KSL*512*384
    float* plq     = partial + KSL * 512 * 384;
    float* plk     = plq + 512 * 96;
    float* plv     = plk + 512 * 96;

    k_proj_gemm<<<dim3(8, 21), 256, 0, stream>>>(x, Wsq, Wsk, Wsv, Wpq, Wpk, Wpv,
                                                 qs, ks, vs, plq, plk, plv);
    k_frames<<<192, 256, 0, stream>>>(plq, plk, plv, rot, trans, qp, kp, vp);
    k_logits<<<dim3(16, 512), 256, 0, stream>>>(pair, qs, ks, qp, kp,
                                                Wpair, bpair, pwts, att);
    k_out<<<512, 256, 0, stream>>>(att, pair, vs, vp, rot, trans, feats);
    k_final_gemm<<<dim3(4, 3, KSL), 256, 0, stream>>>(feats, Wout, partial);
    k_reduce<<<192, 256, 0, stream>>>(partial, bout, (float*)d_out);
}

// Round 5
// 125.654 us; speedup vs baseline: 3.1702x; 1.2216x over previous
//
#include <hip/hip_runtime.h>
#include <hip/hip_bf16.h>
#include <math.h>

#define NN 512
#define DIMX 384
#define HH 8
#define PAIRD 128

#define SCALAR_SCALE 0.144337567297406f   // (3*16)^-0.5
#define POINT_SCALE  0.136082763487954f   // (12*4.5)^-0.5
#define PAIR_SCALE   0.577350269189626f   // 3^-0.5

#define KSL 8
#define KPER 160      // 1280 / KSL

// ---------------- Kernel 1a: unified projection GEMM ----------------
__global__ __launch_bounds__(256) void k_proj_gemm(
    const float* __restrict__ x,
    const float* __restrict__ Wsq, const float* __restrict__ Wsk, const float* __restrict__ Wsv,
    const float* __restrict__ Wpq, const float* __restrict__ Wpk, const float* __restrict__ Wpv,
    float* __restrict__ qs, float* __restrict__ ks, float* __restrict__ vs,
    float* __restrict__ plq, float* __restrict__ plk, float* __restrict__ plv)
{
    const int m0 = blockIdx.x * 64;
    const int t  = blockIdx.y;   // 0..20
    int ldw, c0;
    const float* W;
    float* out;
    if (t < 12) {
        const float* Ws[3] = {Wsq, Wsk, Wsv};
        float* outs[3] = {qs, ks, vs};
        W = Ws[t >> 2]; out = outs[t >> 2]; c0 = (t & 3) * 32; ldw = 128;
    } else {
        const int u = t - 12;
        const float* Wp[3] = {Wpq, Wpk, Wpv};
        float* outp[3] = {plq, plk, plv};
        W = Wp[u / 3]; out = outp[u / 3]; c0 = (u % 3) * 32; ldw = 96;
    }
    const int tid = threadIdx.x;
    __shared__ float xs[32][68];
    __shared__ float Bs[32][36];
    const int tx = tid & 15, ty = tid >> 4;
    float acc[4][2] = {};

    for (int kt = 0; kt < DIMX; kt += 32) {
        #pragma unroll
        for (int it = 0; it < 2; ++it) {
            int l = tid + it * 256;
            int row = l >> 3, kq = l & 7;
            float4 a = *(const float4*)&x[(size_t)(m0 + row) * DIMX + kt + kq * 4];
            xs[kq*4+0][row] = a.x; xs[kq*4+1][row] = a.y;
            xs[kq*4+2][row] = a.z; xs[kq*4+3][row] = a.w;
        }
        {
            int kk = tid >> 3, nq = tid & 7;
            float4 b = *(const float4*)&W[(size_t)(kt + kk) * ldw + c0 + nq * 4];
            *(float4*)&Bs[kk][nq * 4] = b;
        }
        __syncthreads();
        #pragma unroll
        for (int k = 0; k < 32; ++k) {
            float4 a  = *(const float4*)&xs[k][ty * 4];
            float2 bv = *(const float2*)&Bs[k][tx * 2];
            acc[0][0] += a.x * bv.x; acc[0][1] += a.x * bv.y;
            acc[1][0] += a.y * bv.x; acc[1][1] += a.y * bv.y;
            acc[2][0] += a.z * bv.x; acc[2][1] += a.z * bv.y;
            acc[3][0] += a.w * bv.x; acc[3][1] += a.w * bv.y;
        }
        __syncthreads();
    }
    #pragma unroll
    for (int r = 0; r < 4; ++r) {
        float2 v = make_float2(acc[r][0], acc[r][1]);
        *(float2*)&out[(size_t)(m0 + ty * 4 + r) * ldw + c0 + tx * 2] = v;
    }
}

// ---------------- Kernel 1b: frame transform ----------------
__global__ __launch_bounds__(256) void k_frames(
    const float* __restrict__ plq, const float* __restrict__ plk, const float* __restrict__ plv,
    const float* __restrict__ rot, const float* __restrict__ trans,
    float* __restrict__ qp, float* __restrict__ kp, float* __restrict__ vp)
{
    int g = blockIdx.x * 256 + threadIdx.x;
    int m = g >> 14;
    int rem = g & 16383;
    int i = rem >> 5;
    int p = rem & 31;
    const float* pl = (m == 0 ? plq : (m == 1 ? plk : plv));
    float*       o  = (m == 0 ? qp  : (m == 1 ? kp  : vp));
    const float* l = &pl[(size_t)i * 96 + p * 3];
    const float* R = &rot[(size_t)i * 9];
    const float* T = &trans[(size_t)i * 3];
    float l0 = l[0], l1 = l[1], l2 = l[2];
    float* op = o + (size_t)i * 96 + p * 3;
    #pragma unroll
    for (int c = 0; c < 3; ++c)
        op[c] = l0 * R[0 * 3 + c] + l1 * R[1 * 3 + c] + l2 * R[2 * 3 + c] + T[c];
}

// ---------------- Kernel 2: fully-fused attention (logits+softmax+outputs) ----------------
// One block per residue i. Online softmax over 16 j-tiles of 32.
// pair is read from HBM exactly ONCE (double-buffered LDS tile serves both the
// bias GEMV and the out_pair accumulation).
__global__ __launch_bounds__(256) void k_attn(
    const float* __restrict__ pair,
    const float* __restrict__ qs, const float* __restrict__ ks,
    const float* __restrict__ qp, const float* __restrict__ kp,
    const float* __restrict__ vs, const float* __restrict__ vp,
    const float* __restrict__ Wpair, const float* __restrict__ bpair, const float* __restrict__ pwts,
    const float* __restrict__ rot, const float* __restrict__ trans,
    float* __restrict__ feats)
{
    const int i   = blockIdx.x;
    const int tid = threadIdx.x;

    // LDS layout (floats). red4 (final reduce, 8192 floats) aliases the tile
    // buffers, which are dead by then.
    __shared__ float smem[10392];
    float* ptileA = smem;            // [2][32][132]  (2 x 16.9 KB, double-buffered)
    float* wpt    = smem + 8448;     // [8][128]  W_pair transposed (broadcast reads)
    float* wbuf   = smem + 9472;     // [2][8][36]  un-normalized weights (dbuf)
    float* corrb  = smem + 10048;    // [2][8]
    float* qs_s   = smem + 10064;    // [128]
    float* qp_s   = smem + 10192;    // [96]
    float* l_s    = smem + 10288;    // [8]
    float* pts_s  = smem + 10296;    // [96]
    float4* red4  = (float4*)smem;

    for (int l = tid; l < 1024; l += 256) {
        int hh = l >> 7, p = l & 127;
        wpt[hh * 128 + p] = Wpair[p * 8 + hh];
    }
    if (tid < 32) ((float4*)qs_s)[tid] = ((const float4*)(qs + (size_t)i * 128))[tid];
    if (tid < 24) ((float4*)qp_s)[tid] = ((const float4*)(qp + (size_t)i * 96))[tid];

    const int h  = tid >> 5;      // head for logits phase; also jg for acc phase
    const int jj = tid & 31;      // j-in-tile for logits; pq (float4 idx) for acc
    const int jg = h;
    const int pq = jj;

    const float bp_h = bpair[h];
    const float pw_h = log1pf(__expf(pwts[h]));

    float m_run = -1e30f, l_run = 0.f;
    float4 accP[8];
    #pragma unroll
    for (int z = 0; z < 8; ++z) accP[z] = make_float4(0, 0, 0, 0);
    float4 accS = make_float4(0, 0, 0, 0);
    float4 accV = make_float4(0, 0, 0, 0);

    const float4* pair4 = (const float4*)(pair + (size_t)i * NN * PAIRD);
    const float4* vs4   = (const float4*)vs;
    const float4* vp4   = (const float4*)vp;

    // prefetch tile 0 into registers
    float4 r0 = pair4[tid], r1 = pair4[tid + 256], r2 = pair4[tid + 512], r3 = pair4[tid + 768];

    for (int t = 0; t < 16; ++t) {
        float* pt = ptileA + (t & 1) * 4224;
        float* wt = wbuf   + (t & 1) * 288;
        float* cb = corrb  + (t & 1) * 8;

        // write prefetched regs -> LDS tile
        { int l0 = tid;       *(float4*)&pt[(l0 >> 5) * 132 + (l0 & 31) * 4] = r0; }
        { int l1 = tid + 256; *(float4*)&pt[(l1 >> 5) * 132 + (l1 & 31) * 4] = r1; }
        { int l2 = tid + 512; *(float4*)&pt[(l2 >> 5) * 132 + (l2 & 31) * 4] = r2; }
        { int l3 = tid + 768; *(float4*)&pt[(l3 >> 5) * 132 + (l3 & 31) * 4] = r3; }
        __syncthreads();                      // (A) tile ready

        if (t < 15) {                         // prefetch next tile (overlaps compute)
            const float4* psn = pair4 + (size_t)(t + 1) * 1024;
            r0 = psn[tid]; r1 = psn[tid + 256]; r2 = psn[tid + 512]; r3 = psn[tid + 768];
        }

        // ---- logits: thread (h, jj) ----
        const int j = t * 32 + jj;
        float bias = 0.f;
        {
            const float4* prow = (const float4*)&pt[jj * 132];
            const float4* wrow = (const float4*)&wpt[h * 128];
            #pragma unroll 8
            for (int p4 = 0; p4 < 32; ++p4) {
                float4 a = prow[p4], w = wrow[p4];
                bias += a.x * w.x + a.y * w.y + a.z * w.z + a.w * w.w;
            }
        }
        float sc = 0.f;
        {
            const float4* kr4 = (const float4*)(ks + (size_t)j * 128 + h * 16);
            const float4* qr4 = (const float4*)&qs_s[h * 16];
            #pragma unroll
            for (int q = 0; q < 4; ++q) {
                float4 kq = kr4[q], qq = qr4[q];
                sc += qq.x * kq.x + qq.y * kq.y + qq.z * kq.z + qq.w * kq.w;
            }
        }
        float d2 = 0.f;
        {
            const float4* kp4 = (const float4*)(kp + (size_t)j * 96 + h * 12);
            const float4* qp4 = (const float4*)&qp_s[h * 12];
            #pragma unroll
            for (int q = 0; q < 3; ++q) {
                float4 kq = kp4[q], qq = qp4[q];
                float dx = qq.x - kq.x, dy = qq.y - kq.y, dz = qq.z - kq.z, dw = qq.w - kq.w;
                d2 += dx * dx + dy * dy + dz * dz + dw * dw;
            }
        }
        float lg = sc * SCALAR_SCALE + (bias + bp_h) * PAIR_SCALE
                 - 0.5f * POINT_SCALE * pw_h * d2;

        // ---- online softmax update (32-lane head group; replicated regs) ----
        float tm = lg;
        #pragma unroll
        for (int off = 16; off > 0; off >>= 1) tm = fmaxf(tm, __shfl_xor(tm, off));
        float m_new = fmaxf(m_run, tm);
        float corr  = __expf(m_run - m_new);
        float p     = __expf(lg - m_new);
        float ps    = p;
        #pragma unroll
        for (int off = 16; off > 0; off >>= 1) ps += __shfl_xor(ps, off);
        l_run = l_run * corr + ps;
        m_run = m_new;
        wt[h * 36 + jj] = p;
        if (jj == 0) cb[h] = corr;
        __syncthreads();                      // (B) weights ready

        // ---- accumulate: thread (jg, pq) ----
        #pragma unroll
        for (int z = 0; z < 8; ++z) {
            float c = cb[z];
            accP[z].x *= c; accP[z].y *= c; accP[z].z *= c; accP[z].w *= c;
        }
        {
            float c = cb[pq >> 2];
            accS.x *= c; accS.y *= c; accS.z *= c; accS.w *= c;
        }
        if (pq < 24) {
            float c = cb[pq / 3];
            accV.x *= c; accV.y *= c; accV.z *= c; accV.w *= c;
        }
        #pragma unroll
        for (int jo = 0; jo < 4; ++jo) {
            const int jl = jo * 8 + jg;
            float4 pr = *(const float4*)&pt[jl * 132 + pq * 4];
            #pragma unroll
            for (int z = 0; z < 8; ++z) {
                float a = wt[z * 36 + jl];
                accP[z].x += a * pr.x; accP[z].y += a * pr.y;
                accP[z].z += a * pr.z; accP[z].w += a * pr.w;
            }
            {
                float a = wt[(pq >> 2) * 36 + jl];
                float4 v = vs4[(size_t)(t * 32 + jl) * 32 + pq];
                accS.x += a * v.x; accS.y += a * v.y; accS.z += a * v.z; accS.w += a * v.w;
            }
            if (pq < 24) {
                float a = wt[(pq / 3) * 36 + jl];
                float4 v = vp4[(size_t)(t * 32 + jl) * 24 + pq];
                accV.x += a * v.x; accV.y += a * v.y; accV.z += a * v.z; accV.w += a * v.w;
            }
        }
        // no barrier needed here: next tile writes the OTHER buffers
    }

    if (jj == 0) l_s[h] = l_run;
    __syncthreads();                          // all accumulation done; tiles dead

    // out_pair: 8-group tree reduce, normalize, store
    #pragma unroll
    for (int z = 0; z < 8; ++z) red4[(jg * 8 + z) * 32 + pq] = accP[z];
    __syncthreads();
    {
        const int ho = tid >> 5, p4 = tid & 31;
        float4 s = red4[ho * 32 + p4];
        #pragma unroll
        for (int g = 1; g < 8; ++g) {
            float4 v = red4[(g * 8 + ho) * 32 + p4];
            s.x += v.x; s.y += v.y; s.z += v.z; s.w += v.w;
        }
        float inv = 1.f / l_s[ho];
        s.x *= inv; s.y *= inv; s.z *= inv; s.w *= inv;
        ((float4*)&feats[(size_t)i * 1280 + 256])[tid] = s;
    }
    __syncthreads();

    // out_s + out_pts partials
    red4[jg * 32 + pq] = accS;
    if (pq < 24) red4[256 + jg * 24 + pq] = accV;
    __syncthreads();
    if (tid < 32) {
        float4 s = red4[tid];
        #pragma unroll
        for (int g = 1; g < 8; ++g) {
            float4 v = red4[g * 32 + tid];
            s.x += v.x; s.y += v.y; s.z += v.z; s.w += v.w;
        }
        float inv = 1.f / l_s[tid >> 2];
        s.x *= inv; s.y *= inv; s.z *= inv; s.w *= inv;
        ((float4*)&feats[(size_t)i * 1280])[tid] = s;
    } else if (tid < 56) {
        const int pc = tid - 32;
        float4 s = red4[256 + pc];
        #pragma unroll
        for (int g = 1; g < 8; ++g) {
            float4 v = red4[256 + g * 24 + pc];
            s.x += v.x; s.y += v.y; s.z += v.z; s.w += v.w;
        }
        float inv = 1.f / l_s[pc / 3];
        s.x *= inv; s.y *= inv; s.z *= inv; s.w *= inv;
        ((float4*)pts_s)[pc] = s;
    }
    __syncthreads();

    // finalize: back to local frame + norms
    if (tid < 32) {
        const float* R = &rot[(size_t)i * 9];
        const float* T = &trans[(size_t)i * 3];
        float px = pts_s[tid * 3 + 0] - T[0];
        float py = pts_s[tid * 3 + 1] - T[1];
        float pz = pts_s[tid * 3 + 2] - T[2];
        float n2 = 0.f;
        float* fo = feats + (size_t)i * 1280;
        #pragma unroll
        for (int r = 0; r < 3; ++r) {
            float lr = px * R[r * 3 + 0] + py * R[r * 3 + 1] + pz * R[r * 3 + 2];
            fo[128 + tid * 3 + r] = lr;
            n2 += lr * lr;
        }
        fo[224 + tid] = sqrtf(n2 + 1e-8f);
    }
}

// ---------------- Kernel 5a: final GEMM, split-K, 128x128 tile ----------------
__global__ __launch_bounds__(256) void k_final_gemm(
    const float* __restrict__ feats, const float* __restrict__ Wout,
    float* __restrict__ partial)
{
    const int m0 = blockIdx.x * 128;
    const int n0 = blockIdx.y * 128;
    const int ks = blockIdx.z;
    const int tid = threadIdx.x;
    const int k0 = ks * KPER;
    __shared__ float As[16][132];
    __shared__ float Bs[16][132];
    const int tx = tid & 15, ty = tid >> 4;
    float acc[8][8] = {};

    for (int kt = 0; kt < KPER; kt += 16) {
        #pragma unroll
        for (int it = 0; it < 2; ++it) {
            const int l = tid + it * 256;
            const int row = l >> 2, kq = l & 3;
            float4 a = *(const float4*)&feats[(size_t)(m0 + row) * 1280 + k0 + kt + kq * 4];
            As[kq * 4 + 0][row] = a.x; As[kq * 4 + 1][row] = a.y;
            As[kq * 4 + 2][row] = a.z; As[kq * 4 + 3][row] = a.w;
            const int kk = l >> 5, nq = l & 31;
            float4 b = *(const float4*)&Wout[(size_t)(k0 + kt + kk) * 384 + n0 + nq * 4];
            *(float4*)&Bs[kk][nq * 4] = b;
        }
        __syncthreads();
        #pragma unroll
        for (int k = 0; k < 16; ++k) {
            float4 a0 = *(const float4*)&As[k][ty * 8];
            float4 a1 = *(const float4*)&As[k][ty * 8 + 4];
            float4 b0 = *(const float4*)&Bs[k][tx * 8];
            float4 b1 = *(const float4*)&Bs[k][tx * 8 + 4];
            float am[8] = {a0.x, a0.y, a0.z, a0.w, a1.x, a1.y, a1.z, a1.w};
            float bn[8] = {b0.x, b0.y, b0.z, b0.w, b1.x, b1.y, b1.z, b1.w};
            #pragma unroll
            for (int r = 0; r < 8; ++r)
                #pragma unroll
                for (int c = 0; c < 8; ++c)
                    acc[r][c] += am[r] * bn[c];
        }
        __syncthreads();
    }
    float* po = partial + (size_t)ks * (512 * 384);
    #pragma unroll
    for (int r = 0; r < 8; ++r) {
        *(float4*)&po[(size_t)(m0 + ty * 8 + r) * 384 + n0 + tx * 8]     = *(float4*)&acc[r][0];
        *(float4*)&po[(size_t)(m0 + ty * 8 + r) * 384 + n0 + tx * 8 + 4] = *(float4*)&acc[r][4];
    }
}

// ---------------- Kernel 5b: split-K reduce + bias ----------------
__global__ __launch_bounds__(256) void k_reduce(
    const float* __restrict__ partial, const float* __restrict__ bout,
    float* __restrict__ out)
{
    const int f = blockIdx.x * 256 + threadIdx.x;
    const int e = f * 4;
    const int col = e % 384;
    float4 acc = *(const float4*)&bout[col];
    #pragma unroll
    for (int s = 0; s < KSL; ++s) {
        float4 p = *(const float4*)&partial[(size_t)s * (512 * 384) + e];
        acc.x += p.x; acc.y += p.y; acc.z += p.z; acc.w += p.w;
    }
    *(float4*)&out[e] = acc;
}

extern "C" void kernel_launch(void* const* d_in, const int* in_sizes, int n_in,
                              void* d_out, int out_size, void* d_ws, size_t ws_size,
                              hipStream_t stream) {
    const float* x     = (const float*)d_in[0];
    const float* pair  = (const float*)d_in[1];
    const float* rot   = (const float*)d_in[2];
    const float* trans = (const float*)d_in[3];
    const float* Wsq   = (const float*)d_in[4];
    const float* Wsk   = (const float*)d_in[5];
    const float* Wsv   = (const float*)d_in[6];
    const float* Wpq   = (const float*)d_in[7];
    const float* Wpk   = (const float*)d_in[8];
    const float* Wpv   = (const float*)d_in[9];
    const float* Wpair = (const float*)d_in[10];
    const float* bpair = (const float*)d_in[11];
    const float* pwts  = (const float*)d_in[12];
    const float* Wout  = (const float*)d_in[13];
    const float* bout  = (const float*)d_in[14];

    float* ws      = (float*)d_ws;
    float* qs      = ws;                    // 512*128
    float* ks      = qs + 512 * 128;
    float* vs      = ks + 512 * 128;
    float* qp      = vs + 512 * 128;        // 512*96
    float* kp      = qp + 512 * 96;
    float* vp      = kp + 512 * 96;
    float* feats   = vp + 512 * 96;         // 512*1280
    float* partial = feats + 512 * 1280;    // KSL*512*384
    float* plq     = partial + KSL * 512 * 384;
    float* plk     = plq + 512 * 96;
    float* plv     = plk + 512 * 96;

    k_proj_gemm<<<dim3(8, 21), 256, 0, stream>>>(x, Wsq, Wsk, Wsv, Wpq, Wpk, Wpv,
                                                 qs, ks, vs, plq, plk, plv);
    k_frames<<<192, 256, 0, stream>>>(plq, plk, plv, rot, trans, qp, kp, vp);
    k_attn<<<512, 256, 0, stream>>>(pair, qs, ks, qp, kp, vs, vp,
                                    Wpair, bpair, pwts, rot, trans, feats);
    k_final_gemm<<<dim3(4, 3, KSL), 256, 0, stream>>>(feats, Wout, partial);
    k_reduce<<<192, 256, 0, stream>>>(partial, bout, (float*)d_out);
}